// Round 8
// baseline (786.321 us; speedup 1.0000x reference)
//
#include <hip/hip_runtime.h>
#include <math.h>

// ---------------------------------------------------------------------------
// Round 8: occupancy fix for conv1 (256-thr blocks; 64-thr blocks were capped
// at ~16 waves/CU) + software-pipelined tile_conv (prefetch chunk ch+1 into
// registers before the MFMA loop on ch, so global-load latency overlaps MFMA
// instead of stalling at the LDS-write barrier).
//
// Pipeline unchanged otherwise (round 7):
//   conv2/3/4: tile_conv single fp16; corr: tile_conv split fp16 (hi+lo);
//   conv_r1: tile_conv single fp16 split-K 7; conv_r2: direct, split-K 25;
//   conv1 fp32->fp16; dense/tps/masksum fp32.  absmax 4.0 (threshold 14.16).
//
// Workspace (float units), peak 124.2 MB:
//   WT2@0(36864) WT3@36864(147456) WT4@184320(589824)
//   WTr1@774144(802816) WTr2@1576960(102400)
//   FEATs @1679360 (4194304)  S2 @5873664 (8388608)  S1 @14262272 (16777216)
//   S3 overlays S1; post-chain: FEATsp@5873664(8388608,pair)
//   CORRf@14262272(2097152) CORRh@16359424(1048576)
//   R1p@17408000(7x409600) R1h@20275200(204800) R2p@20480000(25x73728)
//   R2f@22323200 GEO@22396928 AX@22397504 AY@22405696
// ---------------------------------------------------------------------------

typedef __attribute__((ext_vector_type(8))) _Float16 f16x8;
typedef __attribute__((ext_vector_type(4))) float f32x4;

__device__ __forceinline__ unsigned short f2h(float f) {
  return __builtin_bit_cast(unsigned short, (_Float16)f);
}
__device__ __forceinline__ float h2f(unsigned short u) {
  return (float)__builtin_bit_cast(_Float16, u);
}

// ---------------------------------------------------------------- weight prep
__global__ __launch_bounds__(256) void wt_single(const float* __restrict__ w,
                                                 unsigned short* __restrict__ wt,
                                                 int K, int C) {
  const int idx = blockIdx.x * 256 + threadIdx.x;
  if (idx < K * C) {
    const int k = idx / C, o = idx % C;
    wt[(size_t)o * K + k] = f2h(w[idx]);
  }
}

// ---------------------------------------------------------------- conv1
// 256-thr blocks: (64 o, 4 i-rows). grid (32 j-groups, 32 i-groups, 32 b).
__global__ __launch_bounds__(256) void conv1_k(const float* __restrict__ in,
                                               const float* __restrict__ w,
                                               unsigned short* __restrict__ out) {
  const int o = threadIdx.x;
  const int j0 = blockIdx.x * 4;
  const int i = blockIdx.y * 4 + threadIdx.y;
  const int b = blockIdx.z;
  const float* __restrict__ inb = in + (size_t)b * 256 * 256 * 3;
  float acc[4] = {0.f, 0.f, 0.f, 0.f};
  const bool full = (2 * j0 + 8) < 256;
#pragma unroll
  for (int di = 0; di < 3; ++di) {
    const int y = 2 * i + di;
    if (y < 256) {
      const float* __restrict__ row = inb + ((size_t)y * 256 + 2 * j0) * 3;
      float xf[28];
      if (full) {
#pragma unroll
        for (int q = 0; q < 14; ++q) {
          const float2 v = ((const float2*)row)[q];
          xf[2 * q] = v.x; xf[2 * q + 1] = v.y;
        }
      } else {
#pragma unroll
        for (int q = 0; q < 12; ++q) {
          const float2 v = ((const float2*)row)[q];
          xf[2 * q] = v.x; xf[2 * q + 1] = v.y;
        }
        xf[24] = xf[25] = xf[26] = xf[27] = 0.f;
      }
#pragma unroll
      for (int c = 0; c < 3; ++c)
#pragma unroll
        for (int dj = 0; dj < 3; ++dj) {
          const float wv = w[(size_t)(((di * 3 + dj) * 3) + c) * 64 + o];
#pragma unroll
          for (int t = 0; t < 4; ++t) acc[t] += xf[(2 * t + dj) * 3 + c] * wv;
        }
    }
  }
#pragma unroll
  for (int t = 0; t < 4; ++t)
    out[(((size_t)b * 128 + i) * 128 + j0 + t) * 64 + o] = f2h(fmaxf(acc[t], 0.f));
}

// ---------------------------------------------------------------- tile conv
// LDS-tiled implicit-GEMM, software-pipelined staging.
template <int BM, int BN, int CIN, int COUT, int KH, int KW, int STRIDE,
          int SAMEPAD, int SPLIT, int SK, int BATB, int OUTF32, int RELU>
__global__ __launch_bounds__(256) void tile_conv(
    const unsigned short* __restrict__ in, const unsigned short* __restrict__ wt,
    unsigned short* __restrict__ outh, float* __restrict__ outf,
    int Hin, int Win, int Hout, int Wout, int aLo, int bLo) {
  constexpr int LDA = 72;
  constexpr int CPT = CIN / 64;
  constexpr int LA = BM / 32;
  constexpr int LB = BN / 32;
  constexpr int KTOT = KH * KW * CIN;
  constexpr int MT = BM / 32;
  constexpr int NT = BN / 32;
  __shared__ _Float16 As[(1 + SPLIT) * BM * LDA];
  __shared__ _Float16 Bs[(1 + SPLIT) * BN * LDA];

  const int t = threadIdx.x;
  const int lane = t & 63, wid = t >> 6;
  const int lrow = lane & 15, quad = lane >> 4;
  const int m0 = blockIdx.x * BM;
  const int n0 = blockIdx.y * BN;

  int pixB[LA], iS[LA], jS[LA], lofA[LA];
#pragma unroll
  for (int i = 0; i < LA; ++i) {
    const int u = t + 256 * i;
    const int r = u >> 3, sl = u & 7;
    const int m = m0 + r;
    const int j = m % Wout;
    const int t2 = m / Wout;
    const int ii = t2 % Hout;
    const int b = t2 / Hout;
    iS[i] = ii * STRIDE;
    jS[i] = j * STRIDE;
    pixB[i] = ((b * Hin + iS[i]) * Win + jS[i]) * CIN + sl * 8;
    lofA[i] = r * LDA + sl * 8;
  }
  const unsigned short* wb = wt;
  if (BATB) wb += (size_t)(m0 / (Hout * Wout)) * COUT * KTOT;
  int bofB[LB], lofB[LB];
#pragma unroll
  for (int i = 0; i < LB; ++i) {
    const int u = t + 256 * i;
    const int r = u >> 3, sl = u & 7;
    bofB[i] = (n0 + r) * KTOT + sl * 8;
    lofB[i] = r * LDA + sl * 8;
  }

  const f16x8 zh = {0, 0, 0, 0, 0, 0, 0, 0};
  f32x4 acc[MT][NT];
#pragma unroll
  for (int mi = 0; mi < MT; ++mi)
#pragma unroll
    for (int ni = 0; ni < NT; ++ni) acc[mi][ni] = {0.f, 0.f, 0.f, 0.f};

  const int mB = (wid >> 1) * (BM / 2);
  const int nB = (wid & 1) * (BN / 2);

  int tap_lo = 0, tap_hi = KH * KW;
  if (SK > 1) {
    tap_lo = (int)blockIdx.z * KH * KW / SK;
    tap_hi = ((int)blockIdx.z + 1) * KH * KW / SK;
  }
  const int chBeg = tap_lo * CPT, chEnd = tap_hi * CPT;

  f16x8 va[LA], vb[LB], va2[LA], vb2[LB];
  f16x8 na[LA], nb[LB], na2[LA], nb2[LB];

  auto ldch = [&](int ch, f16x8* A, f16x8* B, f16x8* A2, f16x8* B2) {
    const int tap = ch / CPT;
    const int c0 = (ch % CPT) * 64;
    const int di = tap / KW, dj = tap % KW;
    const int toff = (di * Win + dj) * CIN + c0;
    const int woff = tap * CIN + c0;
#pragma unroll
    for (int i = 0; i < LA; ++i) {
      const bool ok = !SAMEPAD || ((iS[i] + di < Hin) && (jS[i] + dj < Win));
      A[i] = ok ? *(const f16x8*)(in + pixB[i] + toff) : zh;
      if (SPLIT) A2[i] = ok ? *(const f16x8*)(in + pixB[i] + toff + aLo) : zh;
    }
#pragma unroll
    for (int i = 0; i < LB; ++i) {
      B[i] = *(const f16x8*)(wb + bofB[i] + woff);
      if (SPLIT) B2[i] = *(const f16x8*)(wb + bofB[i] + woff + bLo);
    }
  };

  ldch(chBeg, va, vb, va2, vb2);
  for (int ch = chBeg; ch < chEnd; ++ch) {
    __syncthreads();
#pragma unroll
    for (int i = 0; i < LA; ++i) {
      *(f16x8*)&As[lofA[i]] = va[i];
      if (SPLIT) *(f16x8*)&As[BM * LDA + lofA[i]] = va2[i];
    }
#pragma unroll
    for (int i = 0; i < LB; ++i) {
      *(f16x8*)&Bs[lofB[i]] = vb[i];
      if (SPLIT) *(f16x8*)&Bs[BN * LDA + lofB[i]] = vb2[i];
    }
    __syncthreads();
    if (ch + 1 < chEnd) ldch(ch + 1, na, nb, na2, nb2);
#pragma unroll
    for (int ks = 0; ks < 2; ++ks) {
      f16x8 af[MT], bf[NT], al[MT], bl[NT];
#pragma unroll
      for (int mi = 0; mi < MT; ++mi) {
        const int off = (mB + mi * 16 + lrow) * LDA + ks * 32 + quad * 8;
        af[mi] = *(const f16x8*)&As[off];
        if (SPLIT) al[mi] = *(const f16x8*)&As[BM * LDA + off];
      }
#pragma unroll
      for (int ni = 0; ni < NT; ++ni) {
        const int off = (nB + ni * 16 + lrow) * LDA + ks * 32 + quad * 8;
        bf[ni] = *(const f16x8*)&Bs[off];
        if (SPLIT) bl[ni] = *(const f16x8*)&Bs[BN * LDA + off];
      }
#pragma unroll
      for (int mi = 0; mi < MT; ++mi)
#pragma unroll
        for (int ni = 0; ni < NT; ++ni) {
          if (SPLIT) {
            acc[mi][ni] = __builtin_amdgcn_mfma_f32_16x16x32_f16(af[mi], bl[ni],
                                                                 acc[mi][ni], 0, 0, 0);
            acc[mi][ni] = __builtin_amdgcn_mfma_f32_16x16x32_f16(al[mi], bf[ni],
                                                                 acc[mi][ni], 0, 0, 0);
          }
          acc[mi][ni] = __builtin_amdgcn_mfma_f32_16x16x32_f16(af[mi], bf[ni],
                                                               acc[mi][ni], 0, 0, 0);
        }
    }
#pragma unroll
    for (int i = 0; i < LA; ++i) {
      va[i] = na[i];
      if (SPLIT) va2[i] = na2[i];
    }
#pragma unroll
    for (int i = 0; i < LB; ++i) {
      vb[i] = nb[i];
      if (SPLIT) vb2[i] = nb2[i];
    }
  }
  const size_t slice =
      (SK > 1) ? (size_t)blockIdx.z * ((size_t)gridDim.x * BM * COUT) : 0;
#pragma unroll
  for (int mi = 0; mi < MT; ++mi)
#pragma unroll
    for (int ni = 0; ni < NT; ++ni)
#pragma unroll
      for (int r = 0; r < 4; ++r) {
        const int row = m0 + mB + mi * 16 + quad * 4 + r;
        const int col = n0 + nB + ni * 16 + lrow;
        const size_t idx = (size_t)row * COUT + col;
        float v = acc[mi][ni][r];
        if (SK > 1) {
          outf[slice + idx] = v;
        } else if (OUTF32) {
          outf[idx] = v;
          outh[idx] = f2h(v);
        } else {
          if (RELU) v = fmaxf(v, 0.f);
          outh[idx] = f2h(v);
        }
      }
}

// ---------------------------------------------------------------- direct MFMA
// kept for conv_r2 (tiny), single plane.
template <int MT, int NT, int CIN, int COUT, int KH, int KW, int SK>
__global__ __launch_bounds__(256) void gemm_conv(
    const unsigned short* __restrict__ in, const unsigned short* __restrict__ wt,
    float* __restrict__ outf, int Hin, int Win, int Hout, int Wout) {
  const int KTOT = KH * KW * CIN;
  const int lane = threadIdx.x & 63;
  const int wid = threadIdx.x >> 6;
  const int lrow = lane & 15;
  const int quad = lane >> 4;
  const int m0 = (blockIdx.x * 4 + wid) * (16 * MT);
  const int n0 = blockIdx.y * (16 * NT);

  int pix[MT];
#pragma unroll
  for (int mi = 0; mi < MT; ++mi) {
    const int m = m0 + mi * 16 + lrow;
    const int j = m % Wout;
    const int t = m / Wout;
    const int i = t % Hout;
    const int b = t / Hout;
    pix[mi] = (b * Hin + i) * Win + j;
  }
  const unsigned short* brow[NT];
#pragma unroll
  for (int ni = 0; ni < NT; ++ni)
    brow[ni] = wt + (size_t)(n0 + ni * 16 + lrow) * KTOT + quad * 8;

  f32x4 acc[MT][NT];
#pragma unroll
  for (int mi = 0; mi < MT; ++mi)
#pragma unroll
    for (int ni = 0; ni < NT; ++ni) acc[mi][ni] = {0.f, 0.f, 0.f, 0.f};

  const int tap_lo = (int)blockIdx.z * KH * KW / SK;
  const int tap_hi = ((int)blockIdx.z + 1) * KH * KW / SK;
  for (int tap = tap_lo; tap < tap_hi; ++tap) {
    const int di = tap / KW, dj = tap % KW;
    const unsigned short* ap[MT];
#pragma unroll
    for (int mi = 0; mi < MT; ++mi)
      ap[mi] = in + ((size_t)pix[mi] + di * Win + dj) * CIN + quad * 8;
    const int ko = tap * CIN;
#pragma unroll
    for (int c0 = 0; c0 < CIN; c0 += 32) {
      f16x8 ah[MT], bh[NT];
#pragma unroll
      for (int mi = 0; mi < MT; ++mi) ah[mi] = *(const f16x8*)(ap[mi] + c0);
#pragma unroll
      for (int ni = 0; ni < NT; ++ni) bh[ni] = *(const f16x8*)(brow[ni] + ko + c0);
#pragma unroll
      for (int mi = 0; mi < MT; ++mi)
#pragma unroll
        for (int ni = 0; ni < NT; ++ni)
          acc[mi][ni] = __builtin_amdgcn_mfma_f32_16x16x32_f16(ah[mi], bh[ni],
                                                               acc[mi][ni], 0, 0, 0);
    }
  }
  const size_t slice = (size_t)blockIdx.z * ((size_t)gridDim.x * 64 * MT * COUT);
#pragma unroll
  for (int mi = 0; mi < MT; ++mi)
#pragma unroll
    for (int ni = 0; ni < NT; ++ni)
#pragma unroll
      for (int r = 0; r < 4; ++r) {
        const int row = m0 + mi * 16 + quad * 4 + r;
        const int col = n0 + ni * 16 + lrow;
        outf[slice + (size_t)row * COUT + col] = acc[mi][ni][r];
      }
}

// ---------------------------------------------------------------- split-K epi
__global__ __launch_bounds__(256) void sum_relu_s(const float* __restrict__ p,
                                                  unsigned short* __restrict__ o,
                                                  int n, int parts) {
  const int idx = blockIdx.x * 256 + threadIdx.x;
  if (idx < n) {
    float v = 0.f;
    for (int s = 0; s < parts; ++s) v += p[(size_t)s * n + idx];
    o[idx] = f2h(fmaxf(v, 0.f));
  }
}
__global__ __launch_bounds__(256) void sum_relu_f(const float* __restrict__ p,
                                                  float* __restrict__ o,
                                                  int n, int parts) {
  const int idx = blockIdx.x * 256 + threadIdx.x;
  if (idx < n) {
    float v = 0.f;
    for (int s = 0; s < parts; ++s) v += p[(size_t)s * n + idx];
    o[idx] = fmaxf(v, 0.f);
  }
}

// ---------------------------------------------------------------- l2 normalize
__global__ __launch_bounds__(64) void l2norm_k(const unsigned short* __restrict__ x,
                                               unsigned short* __restrict__ y,
                                               int loOff) {
  const int lane = threadIdx.x;
  const f16x8 v = *(const f16x8*)(x + (size_t)blockIdx.x * 512 + lane * 8);
  float f[8];
  float s = 0.f;
#pragma unroll
  for (int k = 0; k < 8; ++k) {
    f[k] = (float)v[k];
    s += f[k] * f[k];
  }
#pragma unroll
  for (int off = 32; off; off >>= 1) s += __shfl_xor(s, off, 64);
  const float inv = 1.f / (sqrtf(s) + 1e-6f);
  f16x8 vh, vl;
#pragma unroll
  for (int k = 0; k < 8; ++k) {
    const float nv = f[k] * inv;
    const _Float16 hi = (_Float16)nv;
    vh[k] = hi;
    vl[k] = (_Float16)(nv - (float)hi);
  }
  unsigned short* ph = y + (size_t)blockIdx.x * 512 + lane * 8;
  *(f16x8*)ph = vh;
  *(f16x8*)(ph + (size_t)loOff) = vl;
}

// ---------------------------------------------------------------- dense
__global__ __launch_bounds__(64) void dense_k(const float* __restrict__ r2,
                                              const float* __restrict__ wd,
                                              const float* __restrict__ bd,
                                              float* __restrict__ geo) {
  const int o = blockIdx.x;
  const int b = blockIdx.y;
  const int lane = threadIdx.x;
  const float* __restrict__ rb = r2 + (size_t)b * 2304;
  float s = 0.f;
  for (int k = lane; k < 2304; k += 64) s += rb[k] * wd[(size_t)k * 18 + o];
#pragma unroll
  for (int off = 32; off; off >>= 1) s += __shfl_xor(s, off, 64);
  if (lane == 0) geo[b * 18 + o] = s + bd[o];
}

// ---------------------------------------------------------------- TPS
__device__ __forceinline__ float tps_u(float r) { return r * r * logf(r + 1e-6f); }

__global__ __launch_bounds__(64) void tps_k(const float* __restrict__ geo,
                                            float* __restrict__ axb,
                                            float* __restrict__ ayb) {
  const int b = blockIdx.x;
  __shared__ float sDstX[9], sDstY[9];
  __shared__ float sWx[9], sWy[9];
  __shared__ float sAx[3], sAy[3];
  if (threadIdx.x == 0) {
    const float srcx[9] = {0.f, 0.5f, 1.f, 0.f, 0.5f, 1.f, 0.f, 5.f, 1.f};
    const float srcy[9] = {0.f, 0.f, 0.f, 0.5f, 0.5f, 0.5f, 1.f, 1.f, 1.f};
    float dx[9], dy[9];
    float M[12][14];
    for (int r = 0; r < 12; ++r)
      for (int cc = 0; cc < 14; ++cc) M[r][cc] = 0.f;
    for (int p = 0; p < 9; ++p) {
      const float mx = geo[b * 18 + 2 * p], my = geo[b * 18 + 2 * p + 1];
      dx[p] = srcx[p] + mx;
      dy[p] = srcy[p] + my;
      M[p][12] = -mx;
      M[p][13] = -my;
    }
    for (int p = 0; p < 9; ++p) {
      for (int q = 0; q < 9; ++q) {
        const float ddx = dx[p] - dx[q], ddy = dy[p] - dy[q];
        const float r = sqrtf(ddx * ddx + ddy * ddy + 1e-12f);
        M[p][q] = tps_u(r);
      }
      M[p][9] = 1.f;  M[p][10] = dx[p]; M[p][11] = dy[p];
      M[9][p] = 1.f;  M[10][p] = dx[p]; M[11][p] = dy[p];
    }
    for (int k = 0; k < 12; ++k) {
      int piv = k;
      float best = fabsf(M[k][k]);
      for (int r = k + 1; r < 12; ++r) {
        const float v = fabsf(M[r][k]);
        if (v > best) { best = v; piv = r; }
      }
      if (piv != k)
        for (int cc = k; cc < 14; ++cc) {
          const float tmp = M[k][cc]; M[k][cc] = M[piv][cc]; M[piv][cc] = tmp;
        }
      const float d = M[k][k];
      for (int r = k + 1; r < 12; ++r) {
        const float f = M[r][k] / d;
        for (int cc = k; cc < 14; ++cc) M[r][cc] -= f * M[k][cc];
      }
    }
    float thx[12], thy[12];
    for (int k = 11; k >= 0; --k) {
      float sx = M[k][12], sy = M[k][13];
      for (int cc = k + 1; cc < 12; ++cc) {
        sx -= M[k][cc] * thx[cc];
        sy -= M[k][cc] * thy[cc];
      }
      thx[k] = sx / M[k][k];
      thy[k] = sy / M[k][k];
    }
    float swx = 0.f, swy = 0.f;
    for (int p = 1; p < 9; ++p) {
      sWx[p] = thx[p]; sWy[p] = thy[p];
      swx += thx[p];   swy += thy[p];
    }
    sWx[0] = -swx; sWy[0] = -swy;
    for (int p = 0; p < 3; ++p) { sAx[p] = thx[9 + p]; sAy[p] = thy[9 + p]; }
    for (int p = 0; p < 9; ++p) { sDstX[p] = dx[p]; sDstY[p] = dy[p]; }
  }
  __syncthreads();
  for (int p = threadIdx.x; p < 256; p += 64) {
    const int pi = p >> 4, pj = p & 15;
    const float x = pj * (1.f / 15.f), y = pi * (1.f / 15.f);
    float zx = sAx[0] + x * sAx[1] + y * sAx[2];
    float zy = sAy[0] + x * sAy[1] + y * sAy[2];
#pragma unroll
    for (int c = 0; c < 9; ++c) {
      const float ddx = x - sDstX[c], ddy = y - sDstY[c];
      const float r = sqrtf(ddx * ddx + ddy * ddy + 1e-12f);
      const float u = tps_u(r);
      zx += u * sWx[c];
      zy += u * sWy[c];
    }
    axb[b * 256 + p] = (x + zx) * 15.f;
    ayb[b * 256 + p] = (y + zy) * 15.f;
  }
}

// ---------------------------------------------------------------- masked sum
__global__ __launch_bounds__(256) void masksum_k(const float* __restrict__ corr,
                                                 const float* __restrict__ axb,
                                                 const float* __restrict__ ayb,
                                                 float* __restrict__ out) {
  const int b = blockIdx.x;
  const int pB = threadIdx.x;
  const float ax = axb[b * 256 + pB];
  const float ay = ayb[b * 256 + pB];
  const float* __restrict__ cb = corr + (size_t)b * 65536;
  float s = 0.f;
  for (int i = 0; i < 16; ++i) {
    if (fabsf((float)i - ay) <= 1.0f) {
      const float* __restrict__ ci = cb + (size_t)i * 16 * 256 + pB;
      for (int j = 0; j < 16; ++j) {
        if (fabsf((float)j - ax) <= 1.0f) s += ci[(size_t)j * 256];
      }
    }
  }
  __shared__ float sm[256];
  sm[pB] = s;
  __syncthreads();
  for (int off = 128; off; off >>= 1) {
    if (pB < off) sm[pB] += sm[pB + off];
    __syncthreads();
  }
  if (pB == 0) out[b] = sm[0];
}

// ---------------------------------------------------------------- launch
extern "C" void kernel_launch(void* const* d_in, const int* in_sizes, int n_in,
                              void* d_out, int out_size, void* d_ws, size_t ws_size,
                              hipStream_t stream) {
  const float* imgA = (const float*)d_in[0];
  const float* imgB = (const float*)d_in[1];
  const float* W1 = (const float*)d_in[2];
  const float* W2 = (const float*)d_in[3];
  const float* W3 = (const float*)d_in[4];
  const float* W4 = (const float*)d_in[5];
  const float* Wr1 = (const float*)d_in[6];
  const float* Wr2 = (const float*)d_in[7];
  const float* Wd = (const float*)d_in[8];
  const float* bd = (const float*)d_in[9];

  float* ws = (float*)d_ws;
  unsigned short* WT2 = (unsigned short*)(ws + 0);
  unsigned short* WT3 = (unsigned short*)(ws + 36864);
  unsigned short* WT4 = (unsigned short*)(ws + 184320);
  unsigned short* WTr1 = (unsigned short*)(ws + 774144);
  unsigned short* WTr2 = (unsigned short*)(ws + 1576960);
  unsigned short* FEATs = (unsigned short*)(ws + 1679360);
  unsigned short* S2 = (unsigned short*)(ws + 5873664);
  unsigned short* S1 = (unsigned short*)(ws + 14262272);
  unsigned short* S3 = (unsigned short*)(ws + 14262272);    // overlays S1
  unsigned short* FEATsp = (unsigned short*)(ws + 5873664); // overlays S2
  float* CORRf = ws + 14262272;                             // overlays S1/S3
  unsigned short* CORRh = (unsigned short*)(ws + 16359424);
  float* R1p = ws + 17408000;
  unsigned short* R1h = (unsigned short*)(ws + 20275200);
  float* R2p = ws + 20480000;
  float* R2f = ws + 22323200;
  float* GEOb = ws + 22396928;
  float* AXb = ws + 22397504;
  float* AYb = ws + 22405696;

  // weight prep
  wt_single<<<288, 256, 0, stream>>>(W2, WT2, 576, 128);
  wt_single<<<1152, 256, 0, stream>>>(W3, WT3, 1152, 256);
  wt_single<<<4608, 256, 0, stream>>>(W4, WT4, 2304, 512);
  wt_single<<<6272, 256, 0, stream>>>(Wr1, WTr1, 12544, 128);
  wt_single<<<800, 256, 0, stream>>>(Wr2, WTr2, 3200, 64);

  for (int img = 0; img < 2; ++img) {
    const float* src = img ? imgB : imgA;
    conv1_k<<<dim3(32, 32, 32), dim3(64, 4), 0, stream>>>(src, W1, S1);
    // conv2: M = 131072 -> 1024 blocks of 128x128
    tile_conv<128, 128, 64, 128, 3, 3, 2, 1, 0, 1, 0, 0, 1>
        <<<dim3(1024, 1), 256, 0, stream>>>(S1, WT2, S2, nullptr,
                                            128, 128, 64, 64, 0, 0);
    // conv3: M = 32768 -> 256x2
    tile_conv<128, 128, 128, 256, 3, 3, 2, 1, 0, 1, 0, 0, 1>
        <<<dim3(256, 2), 256, 0, stream>>>(S2, WT3, S3, nullptr,
                                           64, 64, 32, 32, 0, 0);
    // conv4: M = 8192 -> 128x4 of 64x128
    tile_conv<64, 128, 256, 512, 3, 3, 2, 1, 0, 1, 0, 0, 1>
        <<<dim3(128, 4), 256, 0, stream>>>(S3, WT4, FEATs + (size_t)img * 4194304,
                                           nullptr, 32, 32, 16, 16, 0, 0);
  }

  // l2norm: FEATs (single) -> FEATsp (split pair, lo at +8388608 el)
  l2norm_k<<<16384, 64, 0, stream>>>(FEATs, FEATsp, 8388608);
  // corr: tiled split GEMM (batched B), fp32 out + single fp16 hi out
  tile_conv<64, 64, 512, 256, 1, 1, 1, 0, 1, 1, 1, 1, 0>
      <<<dim3(128, 4), 256, 0, stream>>>(FEATsp, FEATsp + 4194304, CORRh, CORRf,
                                         16, 16, 16, 16, 8388608, 8388608);
  // conv_r1: tiled single fp16, split-K 7 -> fp32 partials
  tile_conv<64, 128, 256, 128, 7, 7, 1, 0, 0, 7, 0, 0, 0>
      <<<dim3(50, 1, 7), 256, 0, stream>>>(CORRh, WTr1, nullptr, R1p,
                                           16, 16, 10, 10, 0, 0);
  sum_relu_s<<<1600, 256, 0, stream>>>(R1p, R1h, 409600, 7);
  // conv_r2: direct single fp16, split-K 25
  gemm_conv<1, 4, 128, 64, 5, 5, 25>
      <<<dim3(18, 1, 25), 256, 0, stream>>>(R1h, WTr2, R2p, 10, 10, 6, 6);
  sum_relu_f<<<288, 256, 0, stream>>>(R2p, R2f, 73728, 25);
  dense_k<<<dim3(18, 32), 64, 0, stream>>>(R2f, Wd, bd, GEOb);
  tps_k<<<32, 64, 0, stream>>>(GEOb, AXb, AYb);
  masksum_k<<<32, 256, 0, stream>>>(CORRf, AXb, AYb, (float*)d_out);
}